// Round 17
// baseline (385.564 us; speedup 1.0000x reference)
//
#include <hip/hip_runtime.h>

#define NT 256       // 4 waves/block
#define GPB 64       // graphs per block (16 per wave)
#define NB 262144
#define NCOL 64      // graph columns (row stride 256B -> bank = col%32, 2-way free)
#define ROWS 128
// 1/sqrt(1+1e-5)
#define INVC 0.9999950000374997f

typedef __attribute__((ext_vector_type(8))) short bf8;
typedef __attribute__((ext_vector_type(4))) float f4;
typedef unsigned int u32;
typedef __attribute__((ext_vector_type(4))) unsigned int u32x4;

struct P {
  const float* node_feat; const float* edge_feat; const int* ei;
  const float* W_ne; const float* b_ne; const float* g_ne; const float* be_ne;
  const float* W_ee; const float* b_ee;
  const float* msg_W1; const float* msg_b1; const float* msg_W2; const float* msg_b2;
  const float* upd_W1; const float* upd_b1; const float* upd_g1; const float* upd_be1;
  const float* upd_W2; const float* upd_b2; const float* upd_g2; const float* upd_be2;
  const float* Wp; const float* bp; const float* gp; const float* bep;
  const float* mW1; const float* mb1; const float* mg1; const float* mbe1;
  const float* mW2; const float* mb2; const float* mg2; const float* mbe2;
  const float* mW3; const float* mb3; const float* mg3; const float* mbe3;
  const float* mW4; const float* mb4;
  float* out;
};

__device__ __forceinline__ float sigm(float x) {
  return __builtin_amdgcn_rcpf(1.0f + __expf(-x));
}

// ---- packed hi|lo bf16 in one u32: upper 16 = truncated bf16(v), lower 16 = bf16(v - hi)
__device__ __forceinline__ u32 pk(float v) {
  u32 u = __builtin_bit_cast(u32, v);
  u32 hi = u & 0xFFFF0000u;
  float res = v - __builtin_bit_cast(float, hi);
  return hi | (__builtin_bit_cast(u32, res) >> 16);
}
__device__ __forceinline__ float upk(u32 p) {
  return __builtin_bit_cast(float, p & 0xFFFF0000u) +
         __builtin_bit_cast(float, p << 16);
}

// split-bf16 fragment: value ≈ hi + lo
struct F2 { bf8 h, l; };

// assemble fragment from 8 packed u32s: 8 v_perm (2 elems/op per plane)
__device__ __forceinline__ F2 fragFromU32(const u32 (&x)[8]) {
  u32x4 H, L;
#pragma unroll
  for (int i = 0; i < 4; i++) {
    H[i] = __builtin_amdgcn_perm(x[2 * i + 1], x[2 * i], 0x07060302u);  // hi16s
    L[i] = __builtin_amdgcn_perm(x[2 * i + 1], x[2 * i], 0x05040100u);  // lo16s
  }
  F2 r;
  r.h = __builtin_bit_cast(bf8, H);
  r.l = __builtin_bit_cast(bf8, L);
  return r;
}

__device__ __forceinline__ F2 zeroF2() {
  F2 r;
  r.h = __builtin_bit_cast(bf8, (u32x4)(0u));
  r.l = r.h;
  return r;
}

// from fp32 (global weights / node_feat): write-side style pack
__device__ __forceinline__ F2 pack2(const float (&v)[8]) {
  u32 x[8];
#pragma unroll
  for (int i = 0; i < 8; i++) x[i] = pk(v[i]);
  return fragFromU32(x);
}

// D += A*B with split operands (drop lo*lo, ~1e-5 rel)
__device__ __forceinline__ f4 mm(const F2& a, const F2& b, f4 c) {
  c = __builtin_amdgcn_mfma_f32_16x16x32_bf16(a.l, b.h, c, 0, 0, 0);
  c = __builtin_amdgcn_mfma_f32_16x16x32_bf16(a.h, b.l, c, 0, 0, 0);
  c = __builtin_amdgcn_mfma_f32_16x16x32_bf16(a.h, b.h, c, 0, 0, 0);
  return c;
}

// B-fragment from global weights W[k][n] (row-major, LD): k̂ = 8q+i, n fixed/lane
template <int KV>
__device__ __forceinline__ F2 packB(const float* W, int LD, int q, int n) {
  float v[8];
#pragma unroll
  for (int i = 0; i < 8; i++) {
    const int kq = 8 * q + i;
    v[i] = (kq < KV) ? W[kq * LD + n] : 0.f;
  }
  return pack2(v);
}

// A-fragment from packed LDS column xb = &xs32[0][col] (K=32 full)
__device__ __forceinline__ F2 packAr(const u32* xb, int row0) {
  u32 x[8];
#pragma unroll
  for (int i = 0; i < 8; i++) x[i] = xb[(row0 + i) * NCOL];
  return fragFromU32(x);
}
// K=16 variant: rows rowbase..rowbase+15 for q<2, zero for q>=2
__device__ __forceinline__ F2 packA16(const u32* xb, int rowbase, int q) {
  if (q < 2) return packAr(xb, rowbase + 8 * q);
  return zeroF2();
}

// write D-frag packed: row = dimbase+(lane&15), cols cD..cD+3 (16B-aligned base)
__device__ __forceinline__ void wrDp(u32* dst, f4 d) {
  *(uint2*)dst = uint2{pk(d[0]), pk(d[1])};
  *(uint2*)(dst + 2) = uint2{pk(d[2]), pk(d[3])};
}

__device__ __forceinline__ f4 splat4(float b) { return f4{b, b, b, b}; }

// 4 independent waves/block; wave w owns graph columns 16w..16w+15.
// LDS packed-u32 [dim-row][graph-col]: rows 0-79 x, 80-95 scratch, MLP ping-pong
// 0-63/64-127. 32768 B -> 5 blocks/CU. Zero barriers (disjoint columns).
__global__ __launch_bounds__(NT, 1) void gnn_kernel(P pp) {
  __shared__ u32 xs32[ROWS][NCOL];

  const int t = threadIdx.x;
  const int w = t >> 6;
  const int l = t & 63;
  const int q = l >> 4;
  const int m16 = l & 15;
  const int col = w * 16 + m16;       // A-read / mlp4 column (graph gbase+m16)
  const int cD = w * 16 + 4 * q;      // D-frag column base (graphs gbase+4q+r)
  const int gbase = blockIdx.x * GPB + w * 16;

  const u32* xb = &xs32[0][col];
  const f4 z4 = {0.f, 0.f, 0.f, 0.f};

  // edge index -> SGPRs
  int se_[8], de_[8];
#pragma unroll
  for (int e = 0; e < 8; e++) {
    se_[e] = __builtin_amdgcn_readfirstlane(pp.ei[e]);
    de_[e] = __builtin_amdgcn_readfirstlane(pp.ei[8 + e]);
  }
  float dr_[5];
#pragma unroll
  for (int n = 0; n < 5; n++) {
    int c = 0;
#pragma unroll
    for (int e = 0; e < 8; e++) c += (de_[e] == n) ? 1 : 0;
    dr_[n] = 1.0f / (float)(c > 1 ? c : 1);
  }

  // ---------------- node encoder: 5 MFMA tiles, one shared B ----------------
  {
    F2 Bne = packB<7>(pp.W_ne, 16, q, m16);
#pragma unroll 1
    for (int n = 0; n < 5; n++) {
      float v[8];
#pragma unroll
      for (int i = 0; i < 8; i++) {
        const int k = 8 * q + i;
        v[i] = (k < 7) ? pp.node_feat[(size_t)(gbase + m16) * 35 + n * 7 + k] : 0.f;
      }
      F2 a = pack2(v);
      f4 d = mm(a, Bne, z4);
      const float gn = pp.g_ne[n] * INVC, bn = pp.be_ne[n];
      f4 o;
#pragma unroll
      for (int r = 0; r < 4; r++) o[r] = fmaf(gn, d[r], bn);
      wrDp(&xs32[n * 16 + m16][cD], o);
    }
  }

  // ---------------- L message-passing layers ----------------
#pragma unroll 1
  for (int l4 = 0; l4 < 4; l4++) {
    const float* mW1 = pp.msg_W1 + l4 * 576;
    F2 B1a = packB<32>(mW1, 16, q, m16);          // [hi|hj] rows 0-31
    F2 B1e = packB<4>(mW1 + 512, 16, q, m16);     // ea rows 32-35
    F2 B2  = packB<16>(pp.msg_W2 + l4 * 256, 16, q, m16);
    F2 BU1 = packB<32>(pp.upd_W1 + l4 * 512, 16, q, m16);
    F2 BU2 = packB<16>(pp.upd_W2 + l4 * 256, 16, q, m16);
    const float mb1n = pp.msg_b1[l4 * 16 + m16];
    const float mb2n = pp.msg_b2[l4 * 16 + m16];
    const float ub1n = pp.upd_b1[l4 * 16 + m16];
    const float ub2n = pp.upd_b2[l4 * 16 + m16];

    f4 agg[5];
#pragma unroll
    for (int n = 0; n < 5; n++) agg[n] = z4;

    // ---- phase A: per-edge messages ----
#pragma unroll 1
    for (int e = 0; e < 8; e++) {
      const int se = se_[e], de = de_[e];

      // ea A-frag (only lanes q==0, k<4 nonzero)
      float v[8] = {0.f, 0.f, 0.f, 0.f, 0.f, 0.f, 0.f, 0.f};
      if (q == 0) {
        const float* ef = pp.edge_feat + (size_t)(gbase + m16) * 16 + 2 * e;
        const float e0 = ef[0], e1 = ef[1];
#pragma unroll
        for (int j = 0; j < 4; j++)
          v[j] = fmaf(e0, pp.W_ee[j], fmaf(e1, pp.W_ee[4 + j], pp.b_ee[j]));
      }
      F2 aea = pack2(v);

      f4 c1 = splat4(mb1n);
      c1 = mm(aea, B1e, c1);
      const int rowH = (q < 2) ? de * 16 + 8 * q : se * 16 + 8 * (q - 2);
      F2 ah = packAr(xb, rowH);
      c1 = mm(ah, B1a, c1);
#pragma unroll
      for (int r = 0; r < 4; r++) c1[r] = sigm(c1[r]);
      wrDp(&xs32[80 + m16][cD], c1);        // roundtrip (D-layout -> A-layout)
      F2 am = packA16(xb, 80, q);

      f4 c2 = splat4(mb2n);
      c2 = mm(am, B2, c2);
#pragma unroll
      for (int r = 0; r < 4; r++) {
        const float vv = sigm(c2[r]);
        agg[0][r] += (de == 0) ? vv : 0.f;
        agg[1][r] += (de == 1) ? vv : 0.f;
        agg[2][r] += (de == 2) ? vv : 0.f;
        agg[3][r] += (de == 3) ? vv : 0.f;
        agg[4][r] += (de == 4) ? vv : 0.f;
      }
    }

    // ---- phase B: per-node update (fully unrolled: static agg indices) ----
#pragma unroll
    for (int nn = 0; nn < 5; nn++) {
      const float dr = dr_[nn];
      f4 av;
#pragma unroll
      for (int r = 0; r < 4; r++) av[r] = agg[nn][r] * dr;
      wrDp(&xs32[80 + m16][cD], av);        // agg -> scratch
      const int rowU = (q < 2) ? nn * 16 + 8 * q : 80 + 8 * (q - 2);
      F2 au = packAr(xb, rowU);             // [x[nn] | agg]
      f4 c = splat4(ub1n);
      c = mm(au, BU1, c);
      const float G1 = pp.upd_g1[l4 * 5 + nn] * INVC;
      const float Bb1 = pp.upd_be1[l4 * 5 + nn];
#pragma unroll
      for (int r = 0; r < 4; r++) c[r] = sigm(fmaf(G1, c[r], Bb1));
      wrDp(&xs32[80 + m16][cD], c);         // u1 -> scratch
      F2 a2 = packA16(xb, 80, q);
      f4 c2 = splat4(ub2n);
      c2 = mm(a2, BU2, c2);
      const float G2 = pp.upd_g2[l4 * 5 + nn] * INVC;
      const float Bb2 = pp.upd_be2[l4 * 5 + nn];
      u32* xp = &xs32[nn * 16 + m16][cD];
      uint2 a01 = *(uint2*)xp;
      uint2 a23 = *(uint2*)(xp + 2);
      a01.x = pk(upk(a01.x) + sigm(fmaf(G2, c2[0], Bb2)));
      a01.y = pk(upk(a01.y) + sigm(fmaf(G2, c2[1], Bb2)));
      a23.x = pk(upk(a23.x) + sigm(fmaf(G2, c2[2], Bb2)));
      a23.y = pk(upk(a23.y) + sigm(fmaf(G2, c2[3], Bb2)));
      *(uint2*)xp = a01;
      *(uint2*)(xp + 2) = a23;
    }
  }

  // ---------------- pooling: 3 K-tiles over 80 dims -> p1 (scratch 80-95) ----------------
  {
    f4 c = splat4(pp.bp[m16]);
    F2 a0 = packAr(xb, 8 * q);
    F2 b0 = packB<32>(pp.Wp, 16, q, m16);
    c = mm(a0, b0, c);
    F2 a1 = packAr(xb, 32 + 8 * q);
    F2 b1 = packB<32>(pp.Wp + 512, 16, q, m16);
    c = mm(a1, b1, c);
    F2 a2 = packA16(xb, 64, q);
    F2 b2 = packB<16>(pp.Wp + 1024, 16, q, m16);
    c = mm(a2, b2, c);
    const float gpn = pp.gp[m16] * INVC, bepn = pp.bep[m16];
    f4 o;
#pragma unroll
    for (int r = 0; r < 4; r++) o[r] = sigm(fmaf(gpn, c[r], bepn));
    wrDp(&xs32[80 + m16][cD], o);
  }

  // ---------------- mlp1: 16 -> 64 (scratch 80-95 -> rows 0-63) ----------------
  {
    F2 a = packA16(xb, 80, q);
#pragma unroll 1
    for (int nt = 0; nt < 4; nt++) {
      const int nb = nt * 16 + m16;
      F2 b = packB<16>(pp.mW1 + nt * 16, 64, q, m16);
      f4 c = splat4(pp.mb1[nb]);
      c = mm(a, b, c);
      const float g = pp.mg1[nb] * INVC, be = pp.mbe1[nb];
      f4 o;
#pragma unroll
      for (int r = 0; r < 4; r++) o[r] = sigm(fmaf(g, c[r], be));
      wrDp(&xs32[nt * 16 + m16][cD], o);
    }
  }
  // ---------------- mlp2: 64 -> 64 (rows 0-63 -> rows 64-127) ----------------
  {
    F2 a0 = packAr(xb, 8 * q);
    F2 a1 = packAr(xb, 32 + 8 * q);
#pragma unroll 1
    for (int nt = 0; nt < 4; nt++) {
      const int nb = nt * 16 + m16;
      F2 b0 = packB<32>(pp.mW2 + nt * 16, 64, q, m16);
      F2 b1 = packB<32>(pp.mW2 + 32 * 64 + nt * 16, 64, q, m16);
      f4 c = splat4(pp.mb2[nb]);
      c = mm(a0, b0, c);
      c = mm(a1, b1, c);
      const float g = pp.mg2[nb] * INVC, be = pp.mbe2[nb];
      f4 o;
#pragma unroll
      for (int r = 0; r < 4; r++) o[r] = sigm(fmaf(g, c[r], be));
      wrDp(&xs32[64 + nt * 16 + m16][cD], o);
    }
  }
  // ---------------- mlp3: 64 -> 64 (rows 64-127 -> rows 0-63) ----------------
  {
    F2 a0 = packAr(xb, 64 + 8 * q);
    F2 a1 = packAr(xb, 96 + 8 * q);
#pragma unroll 1
    for (int nt = 0; nt < 4; nt++) {
      const int nb = nt * 16 + m16;
      F2 b0 = packB<32>(pp.mW3 + nt * 16, 64, q, m16);
      F2 b1 = packB<32>(pp.mW3 + 32 * 64 + nt * 16, 64, q, m16);
      f4 c = splat4(pp.mb3[nb]);
      c = mm(a0, b0, c);
      c = mm(a1, b1, c);
      const float g = pp.mg3[nb] * INVC, be = pp.mbe3[nb];
      f4 o;
#pragma unroll
      for (int r = 0; r < 4; r++) o[r] = sigm(fmaf(g, c[r], be));
      wrDp(&xs32[nt * 16 + m16][cD], o);
    }
  }
  // ---------------- mlp4: 64 -> 1 (VALU dot + shfl reduce) ----------------
  {
    float s = 0.f;
#pragma unroll
    for (int j = 0; j < 16; j++)
      s = fmaf(upk(xs32[q * 16 + j][col]), pp.mW4[q * 16 + j], s);
    s += __shfl_down(s, 32);
    s += __shfl_down(s, 16);
    if (l < 16) pp.out[gbase + m16] = s + pp.mb4[0];
  }
}

extern "C" void kernel_launch(void* const* d_in, const int* in_sizes, int n_in,
                              void* d_out, int out_size, void* d_ws, size_t ws_size,
                              hipStream_t stream) {
  P p;
  p.node_feat = (const float*)d_in[0];
  p.edge_feat = (const float*)d_in[1];
  p.ei        = (const int*)d_in[2];
  p.W_ne  = (const float*)d_in[3];  p.b_ne  = (const float*)d_in[4];
  p.g_ne  = (const float*)d_in[5];  p.be_ne = (const float*)d_in[6];
  p.W_ee  = (const float*)d_in[7];  p.b_ee  = (const float*)d_in[8];
  p.msg_W1 = (const float*)d_in[9];  p.msg_b1 = (const float*)d_in[10];
  p.msg_W2 = (const float*)d_in[11]; p.msg_b2 = (const float*)d_in[12];
  p.upd_W1 = (const float*)d_in[13]; p.upd_b1 = (const float*)d_in[14];
  p.upd_g1 = (const float*)d_in[15]; p.upd_be1 = (const float*)d_in[16];
  p.upd_W2 = (const float*)d_in[17]; p.upd_b2 = (const float*)d_in[18];
  p.upd_g2 = (const float*)d_in[19]; p.upd_be2 = (const float*)d_in[20];
  p.Wp  = (const float*)d_in[21]; p.bp  = (const float*)d_in[22];
  p.gp  = (const float*)d_in[23]; p.bep = (const float*)d_in[24];
  p.mW1 = (const float*)d_in[25]; p.mb1 = (const float*)d_in[26];
  p.mg1 = (const float*)d_in[27]; p.mbe1 = (const float*)d_in[28];
  p.mW2 = (const float*)d_in[29]; p.mb2 = (const float*)d_in[30];
  p.mg2 = (const float*)d_in[31]; p.mbe2 = (const float*)d_in[32];
  p.mW3 = (const float*)d_in[33]; p.mb3 = (const float*)d_in[34];
  p.mg3 = (const float*)d_in[35]; p.mbe3 = (const float*)d_in[36];
  p.mW4 = (const float*)d_in[37]; p.mb4 = (const float*)d_in[38];
  p.out = (float*)d_out;

  hipLaunchKernelGGL(gnn_kernel, dim3(NB / GPB), dim3(NT), 0, stream, p);
}

// Round 18
// 285.067 us; speedup vs baseline: 1.3525x; 1.3525x over previous
//
#include <hip/hip_runtime.h>

#define NT 256       // 4 waves/block
#define GPB 64       // graphs per block (16 per wave)
#define NB 262144
#define NCOL 66      // row stride 264B -> bank=(2*row+col)%32, q-groups 2-way = free
#define ROWS 128
#define NSLOT 44     // pre-packed weight fragments in d_ws (44 * 2KB = 88KB)
// 1/sqrt(1+1e-5)
#define INVC 0.9999950000374997f

typedef __attribute__((ext_vector_type(8))) short bf8;
typedef __attribute__((ext_vector_type(4))) float f4;
typedef unsigned int u32;
typedef __attribute__((ext_vector_type(4))) unsigned int u32x4;

struct P {
  const float* node_feat; const float* edge_feat; const int* ei;
  const float* W_ne; const float* b_ne; const float* g_ne; const float* be_ne;
  const float* W_ee; const float* b_ee;
  const float* msg_W1; const float* msg_b1; const float* msg_W2; const float* msg_b2;
  const float* upd_W1; const float* upd_b1; const float* upd_g1; const float* upd_be1;
  const float* upd_W2; const float* upd_b2; const float* upd_g2; const float* upd_be2;
  const float* Wp; const float* bp; const float* gp; const float* bep;
  const float* mW1; const float* mb1; const float* mg1; const float* mbe1;
  const float* mW2; const float* mb2; const float* mg2; const float* mbe2;
  const float* mW3; const float* mb3; const float* mg3; const float* mbe3;
  const float* mW4; const float* mb4;
  float* out; u32* ws;
};

__device__ __forceinline__ float sigm(float x) {
  return __builtin_amdgcn_rcpf(1.0f + __expf(-x));
}

// ---- packed hi|lo bf16 in one u32
__device__ __forceinline__ u32 pk(float v) {
  u32 u = __builtin_bit_cast(u32, v);
  u32 hi = u & 0xFFFF0000u;
  float res = v - __builtin_bit_cast(float, hi);
  return hi | (__builtin_bit_cast(u32, res) >> 16);
}
__device__ __forceinline__ float upk(u32 p) {
  return __builtin_bit_cast(float, p & 0xFFFF0000u) +
         __builtin_bit_cast(float, p << 16);
}

struct F2 { bf8 h, l; };

__device__ __forceinline__ F2 fragFromU32(const u32 (&x)[8]) {
  u32x4 H, L;
#pragma unroll
  for (int i = 0; i < 4; i++) {
    H[i] = __builtin_amdgcn_perm(x[2 * i + 1], x[2 * i], 0x07060302u);  // hi16s
    L[i] = __builtin_amdgcn_perm(x[2 * i + 1], x[2 * i], 0x05040100u);  // lo16s
  }
  F2 r;
  r.h = __builtin_bit_cast(bf8, H);
  r.l = __builtin_bit_cast(bf8, L);
  return r;
}

__device__ __forceinline__ F2 pack2(const float (&v)[8]) {
  u32 x[8];
#pragma unroll
  for (int i = 0; i < 8; i++) x[i] = pk(v[i]);
  return fragFromU32(x);
}

// D += A*B with split operands (drop lo*lo, ~1e-5 rel)
__device__ __forceinline__ f4 mm(const F2& a, const F2& b, f4 c) {
  c = __builtin_amdgcn_mfma_f32_16x16x32_bf16(a.l, b.h, c, 0, 0, 0);
  c = __builtin_amdgcn_mfma_f32_16x16x32_bf16(a.h, b.l, c, 0, 0, 0);
  c = __builtin_amdgcn_mfma_f32_16x16x32_bf16(a.h, b.h, c, 0, 0, 0);
  return c;
}

// load a pre-packed B fragment: 2 coalesced dwordx4, zero pack VALU
__device__ __forceinline__ F2 ldFrag(const u32* ws, int slot, int l) {
  const u32x4* pw = (const u32x4*)(ws + slot * 512 + l * 8);
  F2 r;
  r.h = __builtin_bit_cast(bf8, pw[0]);
  r.l = __builtin_bit_cast(bf8, pw[1]);
  return r;
}

// A-fragment from packed LDS column xb = &xs32[0][col] (K=32 full)
__device__ __forceinline__ F2 packAr(const u32* xb, int row0) {
  u32 x[8];
#pragma unroll
  for (int i = 0; i < 8; i++) x[i] = xb[(row0 + i) * NCOL];
  return fragFromU32(x);
}
// K=16 variant: rows rowbase..rowbase+15 for q<2, zero for q>=2
__device__ __forceinline__ F2 packA16(const u32* xb, int rowbase, int q) {
  u32 x[8];
#pragma unroll
  for (int i = 0; i < 8; i++) {
    const int k = 8 * (q & 1) + i;
    u32 v = xb[(rowbase + k) * NCOL];
    x[i] = (q < 2) ? v : 0u;
  }
  return fragFromU32(x);
}

// write D-frag packed: row = dimbase+(lane&15), cols cD..cD+3
__device__ __forceinline__ void wrDp(u32* dst, f4 d) {
  *(uint2*)dst = uint2{pk(d[0]), pk(d[1])};
  *(uint2*)(dst + 2) = uint2{pk(d[2]), pk(d[3])};
}

__device__ __forceinline__ f4 splat4(float b) { return f4{b, b, b, b}; }

// ---- prep kernel: pack all weight B-fragments into ws (once per launch) ----
// slot layout: 0 W_ne | 1+5l: B1a,B1e,B2,BU1,BU2 | 21-23 Wp | 24-27 mW1 |
//              28-35 mW2 (kb*4+nt) | 36-43 mW3
__global__ __launch_bounds__(64) void pack_kernel(P pp) {
  const int s = blockIdx.x;
  const int l = threadIdx.x;
  const int q = l >> 4, n = l & 15;
  const float* W; int LD = 16, KV;
  if (s == 0) { W = pp.W_ne; KV = 7; }
  else if (s < 21) {
    const int l4 = (s - 1) / 5, r = (s - 1) % 5;
    if (r == 0)      { W = pp.msg_W1 + l4 * 576;       KV = 32; }
    else if (r == 1) { W = pp.msg_W1 + l4 * 576 + 512; KV = 4;  }
    else if (r == 2) { W = pp.msg_W2 + l4 * 256;       KV = 16; }
    else if (r == 3) { W = pp.upd_W1 + l4 * 512;       KV = 32; }
    else             { W = pp.upd_W2 + l4 * 256;       KV = 16; }
  } else if (s < 24) {
    const int i = s - 21; W = pp.Wp + i * 512; KV = (i < 2) ? 32 : 16;
  } else if (s < 28) {
    W = pp.mW1 + (s - 24) * 16; LD = 64; KV = 16;
  } else if (s < 36) {
    const int i = s - 28; W = pp.mW2 + (i >> 2) * 2048 + (i & 3) * 16; LD = 64; KV = 32;
  } else {
    const int i = s - 36; W = pp.mW3 + (i >> 2) * 2048 + (i & 3) * 16; LD = 64; KV = 32;
  }
  float v[8];
#pragma unroll
  for (int i = 0; i < 8; i++) {
    const int kq = 8 * q + i;
    v[i] = (kq < KV) ? W[kq * LD + n] : 0.f;
  }
  F2 f = pack2(v);
  u32* dst = pp.ws + s * 512 + l * 8;
  *(u32x4*)dst = __builtin_bit_cast(u32x4, f.h);
  *(u32x4*)(dst + 4) = __builtin_bit_cast(u32x4, f.l);
}

// 4 independent waves/block; wave w owns graph columns 16w..16w+15.
// LDS packed-u32 [row][col]: rows 0-79 x, 80-95 scratch, 96-127 ea (then MLP
// ping-pong 0-63/64-127). 33792 B -> 4 blocks/CU. Zero barriers.
__global__ __launch_bounds__(NT, 1) void gnn_kernel(P pp) {
  __shared__ u32 xs32[ROWS][NCOL];

  const int t = threadIdx.x;
  const int w = t >> 6;
  const int l = t & 63;
  const int q = l >> 4;
  const int m16 = l & 15;
  const int col = w * 16 + m16;
  const int cD = w * 16 + 4 * q;
  const int gbase = blockIdx.x * GPB + w * 16;
  const u32* ws = pp.ws;

  const u32* xb = &xs32[0][col];
  const f4 z4 = {0.f, 0.f, 0.f, 0.f};

  int se_[8], de_[8];
#pragma unroll
  for (int e = 0; e < 8; e++) {
    se_[e] = __builtin_amdgcn_readfirstlane(pp.ei[e]);
    de_[e] = __builtin_amdgcn_readfirstlane(pp.ei[8 + e]);
  }
  float dr_[5];
#pragma unroll
  for (int n = 0; n < 5; n++) {
    int c = 0;
#pragma unroll
    for (int e = 0; e < 8; e++) c += (de_[e] == n) ? 1 : 0;
    dr_[n] = 1.0f / (float)(c > 1 ? c : 1);
  }

  // ---------------- node encoder: 5 MFMA tiles, shared B from ws ----------------
  {
    F2 Bne = ldFrag(ws, 0, l);
#pragma unroll 1
    for (int n = 0; n < 5; n++) {
      float v[8];
#pragma unroll
      for (int i = 0; i < 8; i++) {
        const int k = 8 * q + i;
        v[i] = (k < 7) ? pp.node_feat[(size_t)(gbase + m16) * 35 + n * 7 + k] : 0.f;
      }
      F2 a = pack2(v);
      f4 d = mm(a, Bne, z4);
      const float gn = pp.g_ne[n] * INVC, bn = pp.be_ne[n];
      f4 o;
#pragma unroll
      for (int r = 0; r < 4; r++) o[r] = fmaf(gn, d[r], bn);
      wrDp(&xs32[n * 16 + m16][cD], o);
    }
  }

  // ---------------- ea (layer-invariant) -> packed LDS rows 96..127 ----------------
  {
#pragma unroll
    for (int s2 = 0; s2 < 2; s2++) {
      const int e = 2 * q + s2;
      const float e0 = pp.edge_feat[(size_t)(gbase + m16) * 16 + 2 * e];
      const float e1 = pp.edge_feat[(size_t)(gbase + m16) * 16 + 2 * e + 1];
#pragma unroll
      for (int j = 0; j < 4; j++) {
        const float val = fmaf(e0, pp.W_ee[j], fmaf(e1, pp.W_ee[4 + j], pp.b_ee[j]));
        xs32[96 + e * 4 + j][col] = pk(val);
      }
    }
  }

  // ---------------- L message-passing layers ----------------
#pragma unroll 1
  for (int l4 = 0; l4 < 4; l4++) {
    const int sb = 1 + l4 * 5;
    F2 B1a = ldFrag(ws, sb + 0, l);
    F2 B1e = ldFrag(ws, sb + 1, l);
    F2 B2  = ldFrag(ws, sb + 2, l);
    F2 BU1 = ldFrag(ws, sb + 3, l);
    F2 BU2 = ldFrag(ws, sb + 4, l);
    const float mb1n = pp.msg_b1[l4 * 16 + m16];
    const float mb2n = pp.msg_b2[l4 * 16 + m16];
    const float ub1n = pp.upd_b1[l4 * 16 + m16];
    const float ub2n = pp.upd_b2[l4 * 16 + m16];

    f4 agg[5];
#pragma unroll
    for (int n = 0; n < 5; n++) agg[n] = z4;

    // ---- phase A: per-edge messages ----
#pragma unroll 1
    for (int e = 0; e < 8; e++) {
      const int se = se_[e], de = de_[e];

      // ea A-frag from precomputed LDS (only q==0, k<4 nonzero)
      u32 xv[8];
#pragma unroll
      for (int j = 0; j < 4; j++) {
        const u32 r = xs32[96 + e * 4 + j][col];
        xv[j] = (q == 0) ? r : 0u;
      }
#pragma unroll
      for (int j = 4; j < 8; j++) xv[j] = 0u;
      F2 aea = fragFromU32(xv);

      f4 c1 = splat4(mb1n);
      c1 = mm(aea, B1e, c1);
      const int rowH = (q < 2) ? de * 16 + 8 * q : se * 16 + 8 * (q - 2);
      F2 ah = packAr(xb, rowH);
      c1 = mm(ah, B1a, c1);
#pragma unroll
      for (int r = 0; r < 4; r++) c1[r] = sigm(c1[r]);
      wrDp(&xs32[80 + m16][cD], c1);        // roundtrip (D-layout -> A-layout)
      F2 am = packA16(xb, 80, q);

      f4 c2 = splat4(mb2n);
      c2 = mm(am, B2, c2);
#pragma unroll
      for (int r = 0; r < 4; r++) {
        const float vv = sigm(c2[r]);
        agg[0][r] += (de == 0) ? vv : 0.f;
        agg[1][r] += (de == 1) ? vv : 0.f;
        agg[2][r] += (de == 2) ? vv : 0.f;
        agg[3][r] += (de == 3) ? vv : 0.f;
        agg[4][r] += (de == 4) ? vv : 0.f;
      }
    }

    // ---- phase B: per-node update ----
#pragma unroll
    for (int nn = 0; nn < 5; nn++) {
      const float dr = dr_[nn];
      f4 av;
#pragma unroll
      for (int r = 0; r < 4; r++) av[r] = agg[nn][r] * dr;
      wrDp(&xs32[80 + m16][cD], av);        // agg -> scratch
      const int rowU = (q < 2) ? nn * 16 + 8 * q : 80 + 8 * (q - 2);
      F2 au = packAr(xb, rowU);             // [x[nn] | agg]
      f4 c = splat4(ub1n);
      c = mm(au, BU1, c);
      const float G1 = pp.upd_g1[l4 * 5 + nn] * INVC;
      const float Bb1 = pp.upd_be1[l4 * 5 + nn];
#pragma unroll
      for (int r = 0; r < 4; r++) c[r] = sigm(fmaf(G1, c[r], Bb1));
      wrDp(&xs32[80 + m16][cD], c);         // u1 -> scratch
      F2 a2 = packA16(xb, 80, q);
      f4 c2 = splat4(ub2n);
      c2 = mm(a2, BU2, c2);
      const float G2 = pp.upd_g2[l4 * 5 + nn] * INVC;
      const float Bb2 = pp.upd_be2[l4 * 5 + nn];
      u32* xp = &xs32[nn * 16 + m16][cD];
      uint2 a01 = *(uint2*)xp;
      uint2 a23 = *(uint2*)(xp + 2);
      a01.x = pk(upk(a01.x) + sigm(fmaf(G2, c2[0], Bb2)));
      a01.y = pk(upk(a01.y) + sigm(fmaf(G2, c2[1], Bb2)));
      a23.x = pk(upk(a23.x) + sigm(fmaf(G2, c2[2], Bb2)));
      a23.y = pk(upk(a23.y) + sigm(fmaf(G2, c2[3], Bb2)));
      *(uint2*)xp = a01;
      *(uint2*)(xp + 2) = a23;
    }
  }

  // ---------------- pooling: 3 K-tiles over 80 dims -> scratch 80-95 ----------------
  {
    f4 c = splat4(pp.bp[m16]);
    F2 a0 = packAr(xb, 8 * q);
    c = mm(a0, ldFrag(ws, 21, l), c);
    F2 a1 = packAr(xb, 32 + 8 * q);
    c = mm(a1, ldFrag(ws, 22, l), c);
    F2 a2 = packA16(xb, 64, q);
    c = mm(a2, ldFrag(ws, 23, l), c);
    const float gpn = pp.gp[m16] * INVC, bepn = pp.bep[m16];
    f4 o;
#pragma unroll
    for (int r = 0; r < 4; r++) o[r] = sigm(fmaf(gpn, c[r], bepn));
    wrDp(&xs32[80 + m16][cD], o);
  }

  // ---------------- mlp1: 16 -> 64 (scratch 80-95 -> rows 0-63) ----------------
  {
    F2 a = packA16(xb, 80, q);
#pragma unroll 1
    for (int nt = 0; nt < 4; nt++) {
      const int nb = nt * 16 + m16;
      f4 c = splat4(pp.mb1[nb]);
      c = mm(a, ldFrag(ws, 24 + nt, l), c);
      const float g = pp.mg1[nb] * INVC, be = pp.mbe1[nb];
      f4 o;
#pragma unroll
      for (int r = 0; r < 4; r++) o[r] = sigm(fmaf(g, c[r], be));
      wrDp(&xs32[nt * 16 + m16][cD], o);
    }
  }
  // ---------------- mlp2: 64 -> 64 (rows 0-63 -> rows 64-127) ----------------
  {
    F2 a0 = packAr(xb, 8 * q);
    F2 a1 = packAr(xb, 32 + 8 * q);
#pragma unroll 1
    for (int nt = 0; nt < 4; nt++) {
      const int nb = nt * 16 + m16;
      f4 c = splat4(pp.mb2[nb]);
      c = mm(a0, ldFrag(ws, 28 + nt, l), c);
      c = mm(a1, ldFrag(ws, 32 + nt, l), c);
      const float g = pp.mg2[nb] * INVC, be = pp.mbe2[nb];
      f4 o;
#pragma unroll
      for (int r = 0; r < 4; r++) o[r] = sigm(fmaf(g, c[r], be));
      wrDp(&xs32[64 + nt * 16 + m16][cD], o);
    }
  }
  // ---------------- mlp3: 64 -> 64 (rows 64-127 -> rows 0-63) ----------------
  {
    F2 a0 = packAr(xb, 64 + 8 * q);
    F2 a1 = packAr(xb, 96 + 8 * q);
#pragma unroll 1
    for (int nt = 0; nt < 4; nt++) {
      const int nb = nt * 16 + m16;
      f4 c = splat4(pp.mb3[nb]);
      c = mm(a0, ldFrag(ws, 36 + nt, l), c);
      c = mm(a1, ldFrag(ws, 40 + nt, l), c);
      const float g = pp.mg3[nb] * INVC, be = pp.mbe3[nb];
      f4 o;
#pragma unroll
      for (int r = 0; r < 4; r++) o[r] = sigm(fmaf(g, c[r], be));
      wrDp(&xs32[nt * 16 + m16][cD], o);
    }
  }
  // ---------------- mlp4: 64 -> 1 (VALU dot + shfl reduce) ----------------
  {
    float s = 0.f;
#pragma unroll
    for (int j = 0; j < 16; j++)
      s = fmaf(upk(xs32[q * 16 + j][col]), pp.mW4[q * 16 + j], s);
    s += __shfl_down(s, 32);
    s += __shfl_down(s, 16);
    if (l < 16) pp.out[gbase + m16] = s + pp.mb4[0];
  }
}

extern "C" void kernel_launch(void* const* d_in, const int* in_sizes, int n_in,
                              void* d_out, int out_size, void* d_ws, size_t ws_size,
                              hipStream_t stream) {
  P p;
  p.node_feat = (const float*)d_in[0];
  p.edge_feat = (const float*)d_in[1];
  p.ei        = (const int*)d_in[2];
  p.W_ne  = (const float*)d_in[3];  p.b_ne  = (const float*)d_in[4];
  p.g_ne  = (const float*)d_in[5];  p.be_ne = (const float*)d_in[6];
  p.W_ee  = (const float*)d_in[7];  p.b_ee  = (const float*)d_in[8];
  p.msg_W1 = (const float*)d_in[9];  p.msg_b1 = (const float*)d_in[10];
  p.msg_W2 = (const float*)d_in[11]; p.msg_b2 = (const float*)d_in[12];
  p.upd_W1 = (const float*)d_in[13]; p.upd_b1 = (const float*)d_in[14];
  p.upd_g1 = (const float*)d_in[15]; p.upd_be1 = (const float*)d_in[16];
  p.upd_W2 = (const float*)d_in[17]; p.upd_b2 = (const float*)d_in[18];
  p.upd_g2 = (const float*)d_in[19]; p.upd_be2 = (const float*)d_in[20];
  p.Wp  = (const float*)d_in[21]; p.bp  = (const float*)d_in[22];
  p.gp  = (const float*)d_in[23]; p.bep = (const float*)d_in[24];
  p.mW1 = (const float*)d_in[25]; p.mb1 = (const float*)d_in[26];
  p.mg1 = (const float*)d_in[27]; p.mbe1 = (const float*)d_in[28];
  p.mW2 = (const float*)d_in[29]; p.mb2 = (const float*)d_in[30];
  p.mg2 = (const float*)d_in[31]; p.mbe2 = (const float*)d_in[32];
  p.mW3 = (const float*)d_in[33]; p.mb3 = (const float*)d_in[34];
  p.mg3 = (const float*)d_in[35]; p.mbe3 = (const float*)d_in[36];
  p.mW4 = (const float*)d_in[37]; p.mb4 = (const float*)d_in[38];
  p.out = (float*)d_out;
  p.ws  = (u32*)d_ws;

  hipLaunchKernelGGL(pack_kernel, dim3(NSLOT), dim3(64), 0, stream, p);
  hipLaunchKernelGGL(gnn_kernel, dim3(NB / GPB), dim3(NT), 0, stream, p);
}

// Round 22
// 279.416 us; speedup vs baseline: 1.3799x; 1.0202x over previous
//
#include <hip/hip_runtime.h>

#define NT 256       // 4 waves/block
#define GPB 64       // graphs per block (16 per wave)
#define NB 262144
#define NCOL 66      // row stride 264B -> bank=(2*row+col)%32, q-groups 2-way = free
#define ROWS 128
#define NSLOT 44
// 1/sqrt(1+1e-5)
#define INVC 0.9999950000374997f
// -log2(e): folded into sigmoid-feeding weights so sigm2 = rcp(1+exp2(y))
#define SCL -1.442695040888963f

typedef __attribute__((ext_vector_type(8))) short bf8;
typedef __attribute__((ext_vector_type(4))) float f4;
typedef unsigned int u32;
typedef __attribute__((ext_vector_type(4))) unsigned int u32x4;

struct P {
  const float* node_feat; const float* edge_feat; const int* ei;
  const float* W_ne; const float* b_ne; const float* g_ne; const float* be_ne;
  const float* W_ee; const float* b_ee;
  const float* msg_W1; const float* msg_b1; const float* msg_W2; const float* msg_b2;
  const float* upd_W1; const float* upd_b1; const float* upd_g1; const float* upd_be1;
  const float* upd_W2; const float* upd_b2; const float* upd_g2; const float* upd_be2;
  const float* Wp; const float* bp; const float* gp; const float* bep;
  const float* mW1; const float* mb1; const float* mg1; const float* mbe1;
  const float* mW2; const float* mb2; const float* mg2; const float* mbe2;
  const float* mW3; const float* mb3; const float* mg3; const float* mbe3;
  const float* mW4; const float* mb4;
  float* out; u32* ws;
};

// sigm with pre-scaled input: y = -log2e * z  ->  sigm(z) = rcp(1 + 2^y)
__device__ __forceinline__ float sigm2(float y) {
  return __builtin_amdgcn_rcpf(1.0f + __builtin_amdgcn_exp2f(y));
}

// ---- packed hi|lo bf16 in one u32
__device__ __forceinline__ u32 pk(float v) {
  u32 u = __builtin_bit_cast(u32, v);
  u32 hi = u & 0xFFFF0000u;
  float res = v - __builtin_bit_cast(float, hi);
  return hi | (__builtin_bit_cast(u32, res) >> 16);
}
__device__ __forceinline__ float upk(u32 p) {
  return __builtin_bit_cast(float, p & 0xFFFF0000u) +
         __builtin_bit_cast(float, p << 16);
}

struct F2 { bf8 h, l; };

__device__ __forceinline__ F2 fragFromU32(const u32 (&x)[8]) {
  u32x4 H, L;
#pragma unroll
  for (int i = 0; i < 4; i++) {
    H[i] = __builtin_amdgcn_perm(x[2 * i + 1], x[2 * i], 0x07060302u);
    L[i] = __builtin_amdgcn_perm(x[2 * i + 1], x[2 * i], 0x05040100u);
  }
  F2 r;
  r.h = __builtin_bit_cast(bf8, H);
  r.l = __builtin_bit_cast(bf8, L);
  return r;
}

__device__ __forceinline__ F2 pack2(const float (&v)[8]) {
  u32 x[8];
#pragma unroll
  for (int i = 0; i < 8; i++) x[i] = pk(v[i]);
  return fragFromU32(x);
}

// split x split (drop lo*lo): 3 MFMA, products exact to ~2^-17
__device__ __forceinline__ f4 mm(const F2& a, const F2& b, f4 c) {
  c = __builtin_amdgcn_mfma_f32_16x16x32_bf16(a.l, b.h, c, 0, 0, 0);
  c = __builtin_amdgcn_mfma_f32_16x16x32_bf16(a.h, b.l, c, 0, 0, 0);
  c = __builtin_amdgcn_mfma_f32_16x16x32_bf16(a.h, b.h, c, 0, 0, 0);
  return c;
}

__device__ __forceinline__ F2 ldFrag(const u32* ws, int slot, int l) {
  const u32x4* pw = (const u32x4*)(ws + slot * 512 + l * 8);
  F2 r;
  r.h = __builtin_bit_cast(bf8, pw[0]);
  r.l = __builtin_bit_cast(bf8, pw[1]);
  return r;
}

// A-fragment from packed LDS column (K=32 full, split)
__device__ __forceinline__ F2 packAr(const u32* xb, int row0) {
  u32 x[8];
#pragma unroll
  for (int i = 0; i < 8; i++) x[i] = xb[(row0 + i) * NCOL];
  return fragFromU32(x);
}
// K=16 split: rows rowbase..+15 live in q<2 lanes, zero for q>=2
__device__ __forceinline__ F2 packA16(const u32* xb, int rowbase, int q) {
  u32 x[8];
#pragma unroll
  for (int i = 0; i < 8; i++) {
    const int k = 8 * (q & 1) + i;
    u32 v = xb[(rowbase + k) * NCOL];
    x[i] = (q < 2) ? v : 0u;
  }
  return fragFromU32(x);
}

// write D-frag split-packed (exact to ~2^-16)
__device__ __forceinline__ void wrDp(u32* dst, f4 d) {
  *(uint2*)dst = uint2{pk(d[0]), pk(d[1])};
  *(uint2*)(dst + 2) = uint2{pk(d[2]), pk(d[3])};
}

__device__ __forceinline__ f4 splat4(float b) { return f4{b, b, b, b}; }

// ---- prep kernel: pack weight B-fragments; msg-path slots pre-scaled by SCL,
// B1e carries mb1 as bias row k=4 (A supplies 1.0).
__global__ __launch_bounds__(64) void pack_kernel(P pp) {
  const int s = blockIdx.x;
  const int l = threadIdx.x;
  const int q = l >> 4, n = l & 15;
  const float* W; int LD = 16, KV;
  const float* brow = nullptr;      // optional bias row at k==KV
  float scl = 1.0f;
  if (s == 0) { W = pp.W_ne; KV = 7; }
  else if (s < 21) {
    const int l4 = (s - 1) / 5, r = (s - 1) % 5;
    if (r == 0)      { W = pp.msg_W1 + l4 * 576;       KV = 32; scl = SCL; }
    else if (r == 1) { W = pp.msg_W1 + l4 * 576 + 512; KV = 4;  scl = SCL;
                       brow = pp.msg_b1 + l4 * 16; }
    else if (r == 2) { W = pp.msg_W2 + l4 * 256;       KV = 16; scl = SCL; }
    else if (r == 3) { W = pp.upd_W1 + l4 * 512;       KV = 32; }
    else             { W = pp.upd_W2 + l4 * 256;       KV = 16; }
  } else if (s < 24) {
    const int i = s - 21; W = pp.Wp + i * 512; KV = (i < 2) ? 32 : 16;
  } else if (s < 28) {
    W = pp.mW1 + (s - 24) * 16; LD = 64; KV = 16;
  } else if (s < 36) {
    const int i = s - 28; W = pp.mW2 + (i >> 2) * 2048 + (i & 3) * 16; LD = 64; KV = 32;
  } else {
    const int i = s - 36; W = pp.mW3 + (i >> 2) * 2048 + (i & 3) * 16; LD = 64; KV = 32;
  }
  float v[8];
#pragma unroll
  for (int i = 0; i < 8; i++) {
    const int kq = 8 * q + i;
    float x = 0.f;
    if (kq < KV) x = W[kq * LD + n];
    else if (brow && kq == KV) x = brow[n];
    v[i] = x * scl;
  }
  F2 f = pack2(v);
  u32* dst = pp.ws + s * 512 + l * 8;
  *(u32x4*)dst = __builtin_bit_cast(u32x4, f.h);
  *(u32x4*)(dst + 4) = __builtin_bit_cast(u32x4, f.l);
}

// 4 independent waves/block; wave w owns graph columns 16w..16w+15.
// LDS packed-u32 [row][col]: rows 0-79 x, 80-95 scratch, 96-127 ea (then MLP
// ping-pong 0-63/64-127). FULL SPLIT NUMERICS EVERYWHERE — R19/R20 showed that
// bf16-rounding any 64-wide activation layer puts the 262144-output absmax
// tail at ~2.5e-3 (> 1.92e-3 threshold). Safe cuts only: SCL-folded sigmoid,
// mb1 bias row, x in registers. Zero barriers (disjoint columns).
__global__ __launch_bounds__(NT, 1) void gnn_kernel(P pp) {
  __shared__ u32 xs32[ROWS][NCOL];

  const int t = threadIdx.x;
  const int w = t >> 6;
  const int l = t & 63;
  const int q = l >> 4;
  const int m16 = l & 15;
  const int col = w * 16 + m16;
  const int cD = w * 16 + 4 * q;
  const int gbase = blockIdx.x * GPB + w * 16;
  const u32* ws = pp.ws;

  const u32* xb = &xs32[0][col];
  const f4 z4 = {0.f, 0.f, 0.f, 0.f};

  int se_[8], de_[8];
#pragma unroll
  for (int e = 0; e < 8; e++) {
    se_[e] = __builtin_amdgcn_readfirstlane(pp.ei[e]);
    de_[e] = __builtin_amdgcn_readfirstlane(pp.ei[8 + e]);
  }
  float dr_[5];
#pragma unroll
  for (int n = 0; n < 5; n++) {
    int c = 0;
#pragma unroll
    for (int e = 0; e < 8; e++) c += (de_[e] == n) ? 1 : 0;
    dr_[n] = 1.0f / (float)(c > 1 ? c : 1);
  }

  // ---------------- node encoder: x in regs (xr) + split-packed LDS ----------------
  f4 xr[5];
  {
    F2 Bne = ldFrag(ws, 0, l);
#pragma unroll 1
    for (int n = 0; n < 5; n++) {
      float v[8];
#pragma unroll
      for (int i = 0; i < 8; i++) {
        const int k = 8 * q + i;
        v[i] = (k < 7) ? pp.node_feat[(size_t)(gbase + m16) * 35 + n * 7 + k] : 0.f;
      }
      F2 a = pack2(v);
      f4 d = mm(a, Bne, z4);
      const float gn = pp.g_ne[n] * INVC, bn = pp.be_ne[n];
#pragma unroll
      for (int r = 0; r < 4; r++) xr[n][r] = fmaf(gn, d[r], bn);
      wrDp(&xs32[n * 16 + m16][cD], xr[n]);
    }
  }

  // ---------------- ea (layer-invariant) -> packed LDS rows 96..127 ----------------
  {
#pragma unroll
    for (int s2 = 0; s2 < 2; s2++) {
      const int e = 2 * q + s2;
      const float e0 = pp.edge_feat[(size_t)(gbase + m16) * 16 + 2 * e];
      const float e1 = pp.edge_feat[(size_t)(gbase + m16) * 16 + 2 * e + 1];
#pragma unroll
      for (int j = 0; j < 4; j++) {
        const float val = fmaf(e0, pp.W_ee[j], fmaf(e1, pp.W_ee[4 + j], pp.b_ee[j]));
        xs32[96 + e * 4 + j][col] = pk(val);
      }
    }
  }

  // ---------------- L message-passing layers (full split numerics) ----------------
#pragma unroll 1
  for (int l4 = 0; l4 < 4; l4++) {
    const int sb = 1 + l4 * 5;
    F2 B1a = ldFrag(ws, sb + 0, l);   // pre-scaled by SCL
    F2 B1e = ldFrag(ws, sb + 1, l);   // pre-scaled, bias row k=4
    F2 B2  = ldFrag(ws, sb + 2, l);   // pre-scaled
    F2 BU1 = ldFrag(ws, sb + 3, l);   // raw
    F2 BU2 = ldFrag(ws, sb + 4, l);   // raw
    const float mb2n = pp.msg_b2[l4 * 16 + m16] * SCL;
    const float ub1n = pp.upd_b1[l4 * 16 + m16];
    const float ub2n = pp.upd_b2[l4 * 16 + m16];

    f4 agg[5];
#pragma unroll
    for (int n = 0; n < 5; n++) agg[n] = z4;

    // ---- phase A: per-edge messages ----
#pragma unroll 1
    for (int e = 0; e < 8; e++) {
      const int se = se_[e], de = de_[e];

      // ea A-frag (q==0: k0-3 = ea, k4 = 1.0 for bias row)
      u32 xv[8];
#pragma unroll
      for (int j = 0; j < 4; j++) {
        const u32 r = xs32[96 + e * 4 + j][col];
        xv[j] = (q == 0) ? r : 0u;
      }
      xv[4] = (q == 0) ? 0x3F800000u : 0u;
      xv[5] = xv[6] = xv[7] = 0u;
      F2 aea = fragFromU32(xv);

      f4 c1 = mm(aea, B1e, z4);
      const int rowH = (q < 2) ? de * 16 + 8 * q : se * 16 + 8 * (q - 2);
      F2 ah = packAr(xb, rowH);
      c1 = mm(ah, B1a, c1);
#pragma unroll
      for (int r = 0; r < 4; r++) c1[r] = sigm2(c1[r]);
      wrDp(&xs32[80 + m16][cD], c1);        // split roundtrip
      F2 am = packA16(xb, 80, q);

      f4 c2 = splat4(mb2n);
      c2 = mm(am, B2, c2);
#pragma unroll
      for (int r = 0; r < 4; r++) {
        const float vv = sigm2(c2[r]);
        agg[0][r] += (de == 0) ? vv : 0.f;
        agg[1][r] += (de == 1) ? vv : 0.f;
        agg[2][r] += (de == 2) ? vv : 0.f;
        agg[3][r] += (de == 3) ? vv : 0.f;
        agg[4][r] += (de == 4) ? vv : 0.f;
      }
    }

    // ---- phase B: per-node update ----
#pragma unroll
    for (int nn = 0; nn < 5; nn++) {
      const float dr = dr_[nn];
      f4 av;
#pragma unroll
      for (int r = 0; r < 4; r++) av[r] = agg[nn][r] * dr;
      wrDp(&xs32[80 + m16][cD], av);        // agg -> scratch (split)
      const int rowU = (q < 2) ? nn * 16 + 8 * q : 80 + 8 * (q - 2);
      F2 au = packAr(xb, rowU);             // [x[nn] | agg]
      f4 c = splat4(ub1n);
      c = mm(au, BU1, c);
      const float G1 = pp.upd_g1[l4 * 5 + nn] * (SCL * INVC);
      const float Bb1 = pp.upd_be1[l4 * 5 + nn] * SCL;
#pragma unroll
      for (int r = 0; r < 4; r++) c[r] = sigm2(fmaf(G1, c[r], Bb1));
      wrDp(&xs32[80 + m16][cD], c);         // u1 split
      F2 a2 = packA16(xb, 80, q);
      f4 c2 = splat4(ub2n);
      c2 = mm(a2, BU2, c2);
      const float G2 = pp.upd_g2[l4 * 5 + nn] * (SCL * INVC);
      const float Bb2 = pp.upd_be2[l4 * 5 + nn] * SCL;
#pragma unroll
      for (int r = 0; r < 4; r++) xr[nn][r] += sigm2(fmaf(G2, c2[r], Bb2));
      wrDp(&xs32[nn * 16 + m16][cD], xr[nn]);
    }
  }

  // ---------------- pooling -> scratch 80-95 (split output) ----------------
  {
    f4 c = splat4(pp.bp[m16]);
    F2 a0 = packAr(xb, 8 * q);
    c = mm(a0, ldFrag(ws, 21, l), c);
    F2 a1 = packAr(xb, 32 + 8 * q);
    c = mm(a1, ldFrag(ws, 22, l), c);
    F2 a2 = packA16(xb, 64, q);
    c = mm(a2, ldFrag(ws, 23, l), c);
    const float gpn = pp.gp[m16] * (SCL * INVC);
    const float bepn = pp.bep[m16] * SCL;
    f4 o;
#pragma unroll
    for (int r = 0; r < 4; r++) o[r] = sigm2(fmaf(gpn, c[r], bepn));
    wrDp(&xs32[80 + m16][cD], o);
  }

  // ---------------- mlp1: 16 -> 64 (split in/out) ----------------
  {
    F2 a = packA16(xb, 80, q);
#pragma unroll 1
    for (int nt = 0; nt < 4; nt++) {
      const int nb = nt * 16 + m16;
      f4 c = splat4(pp.mb1[nb]);
      c = mm(a, ldFrag(ws, 24 + nt, l), c);
      const float g = pp.mg1[nb] * (SCL * INVC), be = pp.mbe1[nb] * SCL;
      f4 o;
#pragma unroll
      for (int r = 0; r < 4; r++) o[r] = sigm2(fmaf(g, c[r], be));
      wrDp(&xs32[nt * 16 + m16][cD], o);
    }
  }
  // ---------------- mlp2: 64 -> 64 (rows 0-63 -> rows 64-127) ----------------
  {
    F2 a0 = packAr(xb, 8 * q);
    F2 a1 = packAr(xb, 32 + 8 * q);
#pragma unroll 1
    for (int nt = 0; nt < 4; nt++) {
      const int nb = nt * 16 + m16;
      f4 c = splat4(pp.mb2[nb]);
      c = mm(a0, ldFrag(ws, 28 + nt, l), c);
      c = mm(a1, ldFrag(ws, 32 + nt, l), c);
      const float g = pp.mg2[nb] * (SCL * INVC), be = pp.mbe2[nb] * SCL;
      f4 o;
#pragma unroll
      for (int r = 0; r < 4; r++) o[r] = sigm2(fmaf(g, c[r], be));
      wrDp(&xs32[64 + nt * 16 + m16][cD], o);
    }
  }
  // ---------------- mlp3: 64 -> 64 (rows 64-127 -> rows 0-63) ----------------
  {
    F2 a0 = packAr(xb, 64 + 8 * q);
    F2 a1 = packAr(xb, 96 + 8 * q);
#pragma unroll 1
    for (int nt = 0; nt < 4; nt++) {
      const int nb = nt * 16 + m16;
      f4 c = splat4(pp.mb3[nb]);
      c = mm(a0, ldFrag(ws, 36 + nt, l), c);
      c = mm(a1, ldFrag(ws, 40 + nt, l), c);
      const float g = pp.mg3[nb] * (SCL * INVC), be = pp.mbe3[nb] * SCL;
      f4 o;
#pragma unroll
      for (int r = 0; r < 4; r++) o[r] = sigm2(fmaf(g, c[r], be));
      wrDp(&xs32[nt * 16 + m16][cD], o);
    }
  }
  // ---------------- mlp4: 64 -> 1 (split values: read = upk) ----------------
  {
    float s = 0.f;
#pragma unroll
    for (int j = 0; j < 16; j++)
      s = fmaf(upk(xs32[q * 16 + j][col]), pp.mW4[q * 16 + j], s);
    s += __shfl_down(s, 32);
    s += __shfl_down(s, 16);
    if (l < 16) pp.out[gbase + m16] = s + pp.mb4[0];
  }
}

extern "C" void kernel_launch(void* const* d_in, const int* in_sizes, int n_in,
                              void* d_out, int out_size, void* d_ws, size_t ws_size,
                              hipStream_t stream) {
  P p;
  p.node_feat = (const float*)d_in[0];
  p.edge_feat = (const float*)d_in[1];
  p.ei        = (const int*)d_in[2];
  p.W_ne  = (const float*)d_in[3];  p.b_ne  = (const float*)d_in[4];
  p.g_ne  = (const float*)d_in[5];  p.be_ne = (const float*)d_in[6];
  p.W_ee  = (const float*)d_in[7];  p.b_ee  = (const float*)d_in[8];
  p.msg_W1 = (const float*)d_in[9];  p.msg_b1 = (const float*)d_in[10];
  p.msg_W2 = (const float*)d_in[11]; p.msg_b2 = (const float*)d_in[12];
  p.upd_W1 = (const float*)d_in[13]; p.upd_b1 = (const float*)d_in[14];
  p.upd_g1 = (const float*)d_in[15]; p.upd_be1 = (const float*)d_in[16];
  p.upd_W2 = (const float*)d_in[17]; p.upd_b2 = (const float*)d_in[18];
  p.upd_g2 = (const float*)d_in[19]; p.upd_be2 = (const float*)d_in[20];
  p.Wp  = (const float*)d_in[21]; p.bp  = (const float*)d_in[22];
  p.gp  = (const float*)d_in[23]; p.bep = (const float*)d_in[24];
  p.mW1 = (const float*)d_in[25]; p.mb1 = (const float*)d_in[26];
  p.mg1 = (const float*)d_in[27]; p.mbe1 = (const float*)d_in[28];
  p.mW2 = (const float*)d_in[29]; p.mb2 = (const float*)d_in[30];
  p.mg2 = (const float*)d_in[31]; p.mbe2 = (const float*)d_in[32];
  p.mW3 = (const float*)d_in[33]; p.mb3 = (const float*)d_in[34];
  p.mg3 = (const float*)d_in[35]; p.mbe3 = (const float*)d_in[36];
  p.mW4 = (const float*)d_in[37]; p.mb4 = (const float*)d_in[38];
  p.out = (float*)d_out;
  p.ws  = (u32*)d_ws;

  hipLaunchKernelGGL(pack_kernel, dim3(NSLOT), dim3(64), 0, stream, p);
  hipLaunchKernelGGL(gnn_kernel, dim3(NB / GPB), dim3(NT), 0, stream, p);
}